// Round 1
// baseline (399.032 us; speedup 1.0000x reference)
//
#include <hip/hip_runtime.h>
#include <math.h>

#define B_ 32
#define S_ 8192
#define D_ 1024

// ---------------------------------------------------------------------------
// Kernel 1: scores[b][s] = dot(query[b], keys[b][s])   (raw, pre-softmax)
// One wave per row; q staged in LDS; coalesced float4 key loads.
// ---------------------------------------------------------------------------
__global__ __launch_bounds__(256) void k_scores(const float* __restrict__ q,
                                                const float* __restrict__ keys,
                                                float* __restrict__ scores) {
  const int b = blockIdx.y;
  const int s0 = blockIdx.x * 16;

  __shared__ float qs[D_];
  for (int i = threadIdx.x; i < D_; i += 256) qs[i] = q[b * D_ + i];
  __syncthreads();

  const int wave = threadIdx.x >> 6;
  const int lane = threadIdx.x & 63;
  const float4* qv4 = (const float4*)qs;

  for (int r = wave; r < 16; r += 4) {
    const int s = s0 + r;
    const float4* kp = (const float4*)(keys + ((size_t)b * S_ + (size_t)s) * D_);
    float acc = 0.f;
#pragma unroll
    for (int j = 0; j < 4; ++j) {
      float4 kv = kp[lane + 64 * j];   // contiguous 1 KiB per instruction
      float4 qv = qv4[lane + 64 * j];
      acc += kv.x * qv.x + kv.y * qv.y + kv.z * qv.z + kv.w * qv.w;
    }
#pragma unroll
    for (int off = 32; off > 0; off >>= 1) acc += __shfl_down(acc, off, 64);
    if (lane == 0) scores[(size_t)b * S_ + s] = acc;
  }
}

// ---------------------------------------------------------------------------
// Kernel 2: in-place softmax over each row of [B_, S_]
// One block (256 thr) per batch row; 32 elements per thread held in registers.
// ---------------------------------------------------------------------------
__global__ __launch_bounds__(256) void k_softmax(float* __restrict__ w) {
  const int b = blockIdx.x;
  float* wr = w + (size_t)b * S_;
  const int wave = threadIdx.x >> 6;
  const int lane = threadIdx.x & 63;

  float vals[32];
  float m = -INFINITY;
#pragma unroll
  for (int i = 0; i < 32; ++i) {
    vals[i] = wr[threadIdx.x + 256 * i];
    m = fmaxf(m, vals[i]);
  }
#pragma unroll
  for (int off = 32; off > 0; off >>= 1) m = fmaxf(m, __shfl_down(m, off, 64));

  __shared__ float redm[4];
  if (lane == 0) redm[wave] = m;
  __syncthreads();
  m = fmaxf(fmaxf(redm[0], redm[1]), fmaxf(redm[2], redm[3]));

  float sum = 0.f;
#pragma unroll
  for (int i = 0; i < 32; ++i) {
    vals[i] = expf(vals[i] - m);
    sum += vals[i];
  }
#pragma unroll
  for (int off = 32; off > 0; off >>= 1) sum += __shfl_down(sum, off, 64);

  __shared__ float reds[4];
  if (lane == 0) reds[wave] = sum;
  __syncthreads();
  sum = reds[0] + reds[1] + reds[2] + reds[3];
  const float inv = 1.f / sum;
#pragma unroll
  for (int i = 0; i < 32; ++i) wr[threadIdx.x + 256 * i] = vals[i] * inv;
}

// ---------------------------------------------------------------------------
// Kernel 3: partial[b][c][d] = sum_{s in chunk c} w[b][s] * values[b][s][d]
// Block = 256 threads owning the full D row as float4; loop over chunk rows.
// ---------------------------------------------------------------------------
__global__ __launch_bounds__(256) void k_ctx_partial(const float* __restrict__ w,
                                                     const float* __restrict__ values,
                                                     float* __restrict__ partial,
                                                     int schunk) {
  const int b = blockIdx.y;
  const int c = blockIdx.x;
  const int s0 = c * schunk;
  const int t = threadIdx.x;

  const float4* vp = (const float4*)(values + ((size_t)b * S_ + (size_t)s0) * D_);
  const float* wp = w + (size_t)b * S_ + s0;

  float4 acc = make_float4(0.f, 0.f, 0.f, 0.f);
#pragma unroll 4
  for (int s = 0; s < schunk; ++s) {
    const float wv = wp[s];                       // scalar broadcast
    const float4 v = vp[(size_t)s * 256 + t];     // coalesced 4 KiB/row
    acc.x += wv * v.x;
    acc.y += wv * v.y;
    acc.z += wv * v.z;
    acc.w += wv * v.w;
  }
  ((float4*)partial)[((size_t)b * gridDim.x + c) * 256 + t] = acc;
}

// ---------------------------------------------------------------------------
// Kernel 4: context[b][d] = sum_c partial[b][c][d]
// ---------------------------------------------------------------------------
__global__ __launch_bounds__(256) void k_ctx_reduce(const float* __restrict__ partial,
                                                    float* __restrict__ ctx,
                                                    int nchunks) {
  const int idx = blockIdx.x * 256 + threadIdx.x;   // 0 .. B_*D_-1
  const int b = idx >> 10;
  const int d = idx & (D_ - 1);
  float acc = 0.f;
  for (int c = 0; c < nchunks; ++c)
    acc += partial[(((size_t)b * nchunks + c) << 10) + d];
  ctx[idx] = acc;
}

// ---------------------------------------------------------------------------
extern "C" void kernel_launch(void* const* d_in, const int* in_sizes, int n_in,
                              void* d_out, int out_size, void* d_ws, size_t ws_size,
                              hipStream_t stream) {
  const float* q      = (const float*)d_in[0];
  const float* keys   = (const float*)d_in[1];
  const float* values = (const float*)d_in[2];

  float* out     = (float*)d_out;
  float* ctx     = out;               // [B_, D_]  (first output)
  float* weights = out + B_ * D_;     // [B_, S_]  (second output)

  // Choose S-chunk count so partials fit in workspace (8 MB at 64 chunks).
  int nchunks = 64;
  while (nchunks > 1 && (size_t)B_ * nchunks * D_ * sizeof(float) > ws_size)
    nchunks >>= 1;
  const int schunk = S_ / nchunks;
  float* partial = (float*)d_ws;

  k_scores<<<dim3(S_ / 16, B_), 256, 0, stream>>>(q, keys, weights);
  k_softmax<<<B_, 256, 0, stream>>>(weights);
  k_ctx_partial<<<dim3(nchunks, B_), 256, 0, stream>>>(weights, values, partial, schunk);
  k_ctx_reduce<<<(B_ * D_) / 256, 256, 0, stream>>>(partial, ctx, nchunks);
}

// Round 2
// 398.996 us; speedup vs baseline: 1.0001x; 1.0001x over previous
//
#include <hip/hip_runtime.h>
#include <math.h>

#define B_ 32
#define S_ 8192
#define D_ 1024
#define ROWS_PER_BLK 16
#define NSCORE_BLKS (S_ / ROWS_PER_BLK)   // 512

// ---------------------------------------------------------------------------
// Kernel 1: scores[b][s] = dot(q[b], keys[b][s])  + per-block softmax stats
// One wave per row; q fragment held in registers (no LDS on hot path).
// stats[b][blk] = (max of 16 scores, sum of exp(score - max))
// ---------------------------------------------------------------------------
__global__ __launch_bounds__(256) void k_scores(const float* __restrict__ q,
                                                const float* __restrict__ keys,
                                                float* __restrict__ scores,
                                                float2* __restrict__ stats) {
  const int b = blockIdx.y;
  const int s0 = blockIdx.x * ROWS_PER_BLK;
  const int wave = threadIdx.x >> 6;
  const int lane = threadIdx.x & 63;

  // q fragment: lane needs exactly q4[lane + 64*j], j=0..3 (L2-hot, 128 KB total)
  const float4* q4 = (const float4*)(q + (size_t)b * D_);
  float4 qr[4];
#pragma unroll
  for (int j = 0; j < 4; ++j) qr[j] = q4[lane + 64 * j];

  __shared__ float sc16[ROWS_PER_BLK];

  for (int r = wave; r < ROWS_PER_BLK; r += 4) {
    const int s = s0 + r;
    const float4* kp = (const float4*)(keys + ((size_t)b * S_ + (size_t)s) * D_);
    float acc = 0.f;
#pragma unroll
    for (int j = 0; j < 4; ++j) {
      const float4 kv = kp[lane + 64 * j];   // contiguous 1 KiB per instruction
      acc += kv.x * qr[j].x + kv.y * qr[j].y + kv.z * qr[j].z + kv.w * qr[j].w;
    }
#pragma unroll
    for (int off = 32; off > 0; off >>= 1) acc += __shfl_down(acc, off, 64);
    if (lane == 0) {
      scores[(size_t)b * S_ + s] = acc;
      sc16[r] = acc;
    }
  }
  __syncthreads();

  // wave 0, lanes 0..15: block max + sum(exp(v - max)) via width-16 shuffles
  if (threadIdx.x < 64) {
    const float v = (lane < ROWS_PER_BLK) ? sc16[lane] : -INFINITY;
    float m = v;
#pragma unroll
    for (int off = 8; off > 0; off >>= 1) m = fmaxf(m, __shfl_xor(m, off, 16));
    float p = (lane < ROWS_PER_BLK) ? expf(v - m) : 0.f;
#pragma unroll
    for (int off = 8; off > 0; off >>= 1) p += __shfl_xor(p, off, 16);
    if (lane == 0) stats[(size_t)b * NSCORE_BLKS + blockIdx.x] = make_float2(m, p);
  }
}

// ---------------------------------------------------------------------------
// Kernel 2 (tiny): merge 512 per-block stats into per-row (max, 1/sum).
// One wave per batch row; online merge (rescale) then butterfly merge.
// ---------------------------------------------------------------------------
__global__ __launch_bounds__(64) void k_combine(const float2* __restrict__ stats,
                                                float2* __restrict__ rowstats) {
  const int b = blockIdx.x;
  const int lane = threadIdx.x;
  float m = -INFINITY, ssum = 0.f;
  for (int c = lane; c < NSCORE_BLKS; c += 64) {
    const float2 st = stats[(size_t)b * NSCORE_BLKS + c];
    if (st.x > m) { ssum = ssum * expf(m - st.x) + st.y; m = st.x; }
    else          { ssum += st.y * expf(st.x - m); }
  }
#pragma unroll
  for (int off = 32; off > 0; off >>= 1) {
    const float om = __shfl_xor(m, off, 64);
    const float os = __shfl_xor(ssum, off, 64);
    const float nm = fmaxf(m, om);
    ssum = ssum * expf(m - nm) + os * expf(om - nm);
    m = nm;
  }
  if (lane == 0) rowstats[b] = make_float2(m, 1.f / ssum);
}

// ---------------------------------------------------------------------------
// Kernel 3: normalize scores -> weights (in place, also staged to LDS),
// then partial[b][c][d] = sum_{s in chunk} w[s] * values[b][s][d].
// ---------------------------------------------------------------------------
__global__ __launch_bounds__(256) void k_ctx_partial(float* __restrict__ w,
                                                     const float* __restrict__ values,
                                                     const float2* __restrict__ rowstats,
                                                     float* __restrict__ partial,
                                                     int schunk) {
  const int b = blockIdx.y;
  const int c = blockIdx.x;
  const int s0 = c * schunk;
  const int t = threadIdx.x;

  __shared__ float wlds[1024];   // schunk <= 1024 guaranteed by launcher
  const float2 rs = rowstats[b];
  for (int i = t; i < schunk; i += 256) {
    const float sc = w[(size_t)b * S_ + s0 + i];
    const float wi = expf(sc - rs.x) * rs.y;
    wlds[i] = wi;
    w[(size_t)b * S_ + s0 + i] = wi;   // weights output (in-place over raw scores)
  }
  __syncthreads();

  const float4* vp = (const float4*)(values + ((size_t)b * S_ + (size_t)s0) * D_);
  float4 acc = make_float4(0.f, 0.f, 0.f, 0.f);
#pragma unroll 4
  for (int s = 0; s < schunk; ++s) {
    const float wv = wlds[s];                     // same-address LDS broadcast
    const float4 v = vp[(size_t)s * 256 + t];     // coalesced 4 KiB/row
    acc.x += wv * v.x;
    acc.y += wv * v.y;
    acc.z += wv * v.z;
    acc.w += wv * v.w;
  }
  ((float4*)partial)[((size_t)b * gridDim.x + c) * 256 + t] = acc;
}

// ---------------------------------------------------------------------------
// Kernel 4: context[b][d] = sum_c partial[b][c][d]
// ---------------------------------------------------------------------------
__global__ __launch_bounds__(256) void k_ctx_reduce(const float* __restrict__ partial,
                                                    float* __restrict__ ctx,
                                                    int nchunks) {
  const int idx = blockIdx.x * 256 + threadIdx.x;   // 0 .. B_*D_-1
  const int b = idx >> 10;
  const int d = idx & (D_ - 1);
  float acc = 0.f;
  for (int c = 0; c < nchunks; ++c)
    acc += partial[(((size_t)b * nchunks + c) << 10) + d];
  ctx[idx] = acc;
}

// ---------------------------------------------------------------------------
extern "C" void kernel_launch(void* const* d_in, const int* in_sizes, int n_in,
                              void* d_out, int out_size, void* d_ws, size_t ws_size,
                              hipStream_t stream) {
  const float* q      = (const float*)d_in[0];
  const float* keys   = (const float*)d_in[1];
  const float* values = (const float*)d_in[2];

  float* out     = (float*)d_out;
  float* ctx     = out;               // [B_, D_]  (first output)
  float* weights = out + B_ * D_;     // [B_, S_]  (second output; raw scores live
                                      //  here between k_scores and k_ctx_partial)

  // Workspace layout: [partials | block stats | row stats]
  const size_t stats_bytes    = (size_t)B_ * NSCORE_BLKS * sizeof(float2);  // 128 KB
  const size_t rowstats_bytes = (size_t)B_ * sizeof(float2);                // 256 B
  int nchunks = 64;
  while (nchunks > 8 &&
         (size_t)B_ * nchunks * D_ * sizeof(float) + stats_bytes + rowstats_bytes > ws_size)
    nchunks >>= 1;
  const int schunk = S_ / nchunks;    // <= 1024 (fits wlds)

  float*  partial  = (float*)d_ws;
  float2* stats    = (float2*)((char*)d_ws + (size_t)B_ * nchunks * D_ * sizeof(float));
  float2* rowstats = stats + (size_t)B_ * NSCORE_BLKS;

  k_scores<<<dim3(NSCORE_BLKS, B_), 256, 0, stream>>>(q, keys, weights, stats);
  k_combine<<<B_, 64, 0, stream>>>(stats, rowstats);
  k_ctx_partial<<<dim3(nchunks, B_), 256, 0, stream>>>(weights, values, rowstats, partial, schunk);
  k_ctx_reduce<<<(B_ * D_) / 256, 256, 0, stream>>>(partial, ctx, nchunks);
}

// Round 3
// 345.130 us; speedup vs baseline: 1.1562x; 1.1561x over previous
//
#include <hip/hip_runtime.h>
#include <math.h>

#define B_ 32
#define S_ 8192
#define D_ 1024
#define NCH 64
#define SCHUNK 128              // S_ / NCH
#define TILE 16
#define NTILES (SCHUNK / TILE)  // 8

typedef float f32x4 __attribute__((ext_vector_type(4)));

// ---------------------------------------------------------------------------
// Fused kernel: per (b, chunk) stream keys AND values once.
// Per 16-row tile: scores (wave-per-row dot, shuffle reduce) -> raw scores to
// global + LDS; then online-softmax accumulation of the chunk context.
// Outputs: raw scores (in weights buffer), per-chunk (m, sum), per-chunk
// unnormalized context partial.
// ---------------------------------------------------------------------------
__global__ __launch_bounds__(256) void k_fused(
    const float* __restrict__ q, const float* __restrict__ keys,
    const float* __restrict__ values, float* __restrict__ scores,
    f32x4* __restrict__ partial, float2* __restrict__ stats) {
  const int b = blockIdx.y;
  const int c = blockIdx.x;
  const int s0 = c * SCHUNK;
  const int t = threadIdx.x;
  const int wave = t >> 6;
  const int lane = t & 63;

  // q fragment in registers: lane needs exactly q4[lane + 64j] (L2-hot)
  const f32x4* q4 = (const f32x4*)(q + (size_t)b * D_);
  f32x4 qr[4];
#pragma unroll
  for (int j = 0; j < 4; ++j) qr[j] = q4[lane + 64 * j];

  __shared__ float wtile[TILE];

  f32x4 acc = {0.f, 0.f, 0.f, 0.f};
  float m_run = -INFINITY, s_run = 0.f;

  const float* kbase = keys   + ((size_t)b * S_ + s0) * D_;
  const float* vbase = values + ((size_t)b * S_ + s0) * D_;
  float* srow = scores + (size_t)b * S_ + s0;

  for (int tl = 0; tl < NTILES; ++tl) {
    const int r0 = tl * TILE;

    // ---- phase K: 4 waves x 4 rows each, wave-per-row dot products
#pragma unroll
    for (int rr = 0; rr < 4; ++rr) {
      const int rl = rr * 4 + wave;  // local row in tile [0,16)
      const f32x4* kp = (const f32x4*)(kbase + (size_t)(r0 + rl) * D_);
      float a = 0.f;
#pragma unroll
      for (int j = 0; j < 4; ++j) {
        const f32x4 kv = __builtin_nontemporal_load(kp + lane + 64 * j);
        a += kv.x * qr[j].x + kv.y * qr[j].y + kv.z * qr[j].z + kv.w * qr[j].w;
      }
#pragma unroll
      for (int off = 32; off > 0; off >>= 1) a += __shfl_down(a, off, 64);
      if (lane == 0) {
        wtile[rl] = a;
        srow[r0 + rl] = a;   // raw score (normalized later by finalize)
      }
    }
    __syncthreads();

    // ---- phase V: online-softmax accumulate; thread t owns column slot t
    float mx = m_run;
#pragma unroll
    for (int i = 0; i < TILE; ++i) mx = fmaxf(mx, wtile[i]);
    const float resc = __expf(m_run - mx);   // exp(-inf)=0 on first tile: OK
    acc *= resc;
    float psum = s_run * resc;
    const f32x4* vp = (const f32x4*)(vbase + (size_t)r0 * D_);
#pragma unroll
    for (int i = 0; i < TILE; ++i) {
      const float w = __expf(wtile[i] - mx);  // LDS same-address broadcast
      psum += w;
      const f32x4 v = __builtin_nontemporal_load(vp + (size_t)i * 256 + t);
      acc += w * v;
    }
    m_run = mx;
    s_run = psum;
    __syncthreads();   // before next tile overwrites wtile
  }

  partial[((size_t)b * NCH + c) * 256 + t] = acc;
  if (t == 0) stats[b * NCH + c] = make_float2(m_run, s_run);
}

// ---------------------------------------------------------------------------
// Finalize: merge per-chunk stats -> global (m, 1/sum) per row; rescale+reduce
// partials into context; normalize raw scores -> weights in place. ~10 MB.
// Grid: dim3(8, B_). Block x handles d in [x*128, x*128+128) and
// s in [x*1024, (x+1)*1024).
// ---------------------------------------------------------------------------
__global__ __launch_bounds__(256) void k_finalize(
    const float* __restrict__ scores,   // aliases weights (in-place)
    const float* __restrict__ partial,
    const float2* __restrict__ stats,
    float* __restrict__ ctx,
    float* __restrict__ weights) {
  const int b = blockIdx.y;
  const int x = blockIdx.x;  // [0,8)
  const int t = threadIdx.x;

  // global row stats (thread-redundant, deterministic)
  const float2* st = stats + (size_t)b * NCH;
  float m = -INFINITY;
  for (int cc = 0; cc < NCH; ++cc) m = fmaxf(m, st[cc].x);
  float ssum = 0.f;
  for (int cc = 0; cc < NCH; ++cc) ssum += st[cc].y * __expf(st[cc].x - m);
  const float inv = 1.f / ssum;

  // per-chunk combined scale factors in LDS
  __shared__ float scl[NCH];
  if (t < NCH) scl[t] = __expf(st[t].x - m) * inv;
  __syncthreads();

  // context slice: threads 0..127 own d = x*128 + t
  if (t < 128) {
    const int d = x * 128 + t;
    float a = 0.f;
    for (int cc = 0; cc < NCH; ++cc)
      a += partial[((size_t)b * NCH + cc) * D_ + d] * scl[cc];
    ctx[(size_t)b * D_ + d] = a;
  }

  // weights slice: s = x*1024 + i*256 + t  (elementwise in-place over scores)
#pragma unroll
  for (int i = 0; i < 4; ++i) {
    const size_t s = (size_t)b * S_ + x * 1024 + i * 256 + t;
    weights[s] = __expf(scores[s] - m) * inv;
  }
}

// ---------------------------------------------------------------------------
extern "C" void kernel_launch(void* const* d_in, const int* in_sizes, int n_in,
                              void* d_out, int out_size, void* d_ws, size_t ws_size,
                              hipStream_t stream) {
  const float* q      = (const float*)d_in[0];
  const float* keys   = (const float*)d_in[1];
  const float* values = (const float*)d_in[2];

  float* out     = (float*)d_out;
  float* ctx     = out;               // [B_, D_]
  float* weights = out + B_ * D_;     // [B_, S_] (holds raw scores between kernels)

  f32x4*  partial = (f32x4*)d_ws;                                   // 8 MB
  float2* stats   = (float2*)((char*)d_ws +
                              (size_t)B_ * NCH * D_ * sizeof(float)); // 16 KB

  k_fused<<<dim3(NCH, B_), 256, 0, stream>>>(q, keys, values, weights,
                                             partial, stats);
  k_finalize<<<dim3(8, B_), 256, 0, stream>>>(weights, (const float*)partial,
                                              stats, ctx, weights);
}

// Round 4
// 337.561 us; speedup vs baseline: 1.1821x; 1.0224x over previous
//
#include <hip/hip_runtime.h>
#include <math.h>

#define B_ 32
#define S_ 8192
#define D_ 1024
#define NCH 64
#define SCHUNK 128              // S_ / NCH
#define TILE 16
#define NTILES (SCHUNK / TILE)  // 8

typedef float f32x4 __attribute__((ext_vector_type(4)));

// ---------------------------------------------------------------------------
// Fused kernel: per (b, chunk) stream keys AND values once, software-pipelined:
// iteration t issues K-dot(t+1) loads first (oldest in vmcnt queue), then
// V-accumulates tile t; ONE barrier per iteration (double-buffered wtile).
// Outputs: raw scores (into weights buffer), per-chunk (m, sum), per-chunk
// unnormalized context partial.
// ---------------------------------------------------------------------------
__global__ __launch_bounds__(256) void k_fused(
    const float* __restrict__ q, const float* __restrict__ keys,
    const float* __restrict__ values, float* __restrict__ scores,
    f32x4* __restrict__ partial, float2* __restrict__ stats) {
  const int b = blockIdx.y;
  const int c = blockIdx.x;
  const int s0 = c * SCHUNK;
  const int t = threadIdx.x;
  const int wave = t >> 6;
  const int lane = t & 63;

  // q fragment in registers: lane needs exactly q4[lane + 64j] (L2-hot)
  const f32x4* q4 = (const f32x4*)(q + (size_t)b * D_);
  f32x4 qr[4];
#pragma unroll
  for (int j = 0; j < 4; ++j) qr[j] = q4[lane + 64 * j];

  __shared__ float wtile[2][TILE];

  f32x4 acc = {0.f, 0.f, 0.f, 0.f};
  float m_run = -INFINITY, s_run = 0.f;

  const float* kbase = keys   + ((size_t)b * S_ + s0) * D_;
  const float* vbase = values + ((size_t)b * S_ + s0) * D_;
  float* srow = scores + (size_t)b * S_ + s0;

  // ---- K-dot for one 16-row tile into wtile[buf]: 4 waves x 4 rows
#define DOT_TILE(TL, BUF)                                                     \
  {                                                                           \
    const int r0_ = (TL) * TILE;                                              \
    _Pragma("unroll") for (int rr = 0; rr < 4; ++rr) {                        \
      const int rl = rr * 4 + wave;                                           \
      const f32x4* kp = (const f32x4*)(kbase + (size_t)(r0_ + rl) * D_);      \
      float a_ = 0.f;                                                         \
      _Pragma("unroll") for (int j = 0; j < 4; ++j) {                         \
        const f32x4 kv = __builtin_nontemporal_load(kp + lane + 64 * j);      \
        a_ += kv.x * qr[j].x + kv.y * qr[j].y + kv.z * qr[j].z +              \
              kv.w * qr[j].w;                                                 \
      }                                                                       \
      _Pragma("unroll") for (int off = 32; off > 0; off >>= 1)                \
          a_ += __shfl_down(a_, off, 64);                                     \
      if (lane == 0) wtile[BUF][rl] = a_;                                     \
    }                                                                         \
  }

  DOT_TILE(0, 0);
  __syncthreads();

  for (int tl = 0; tl < NTILES; ++tl) {
    const int cur = tl & 1;

    // issue next tile's K loads FIRST (oldest in vmcnt queue -> the shuffle
    // reduce waits only on them while this tile's V loads stay in flight)
    if (tl + 1 < NTILES) DOT_TILE(tl + 1, cur ^ 1);

    // ---- V accumulate tile tl from wtile[cur]; thread t owns f32x4 slot t
    float mx = m_run;
#pragma unroll
    for (int i = 0; i < TILE; ++i) mx = fmaxf(mx, wtile[cur][i]);
    const float resc = __expf(m_run - mx);   // exp(-inf)=0 on first tile: OK
    acc *= resc;
    float psum = s_run * resc;
    const f32x4* vp = (const f32x4*)(vbase + (size_t)tl * TILE * D_);
#pragma unroll
    for (int i = 0; i < TILE; ++i) {
      const float w = __expf(wtile[cur][i] - mx);  // same-address broadcast
      psum += w;
      const f32x4 v = __builtin_nontemporal_load(vp + (size_t)i * 256 + t);
      acc += w * v;
    }
    m_run = mx;
    s_run = psum;

    // coalesced raw-score store (one 64B transaction per tile)
    if (t < TILE) srow[tl * TILE + t] = wtile[cur][t];

    __syncthreads();   // single barrier: publishes wtile[cur^1], frees wtile[cur]
  }

  partial[((size_t)b * NCH + c) * 256 + t] = acc;
  if (t == 0) stats[b * NCH + c] = make_float2(m_run, s_run);
}

// ---------------------------------------------------------------------------
// Finalize: merge per-chunk stats -> global (m, 1/sum) per row; rescale+reduce
// partials into context; normalize raw scores -> weights in place. ~18 MB.
// Grid: dim3(8, B_).
// ---------------------------------------------------------------------------
__global__ __launch_bounds__(256) void k_finalize(
    const float* __restrict__ scores,   // aliases weights (in-place)
    const float* __restrict__ partial,
    const float2* __restrict__ stats,
    float* __restrict__ ctx,
    float* __restrict__ weights) {
  const int b = blockIdx.y;
  const int x = blockIdx.x;  // [0,8)
  const int t = threadIdx.x;

  // global row stats (thread-redundant, deterministic)
  const float2* st = stats + (size_t)b * NCH;
  float m = -INFINITY;
  for (int cc = 0; cc < NCH; ++cc) m = fmaxf(m, st[cc].x);
  float ssum = 0.f;
  for (int cc = 0; cc < NCH; ++cc) ssum += st[cc].y * __expf(st[cc].x - m);
  const float inv = 1.f / ssum;

  // per-chunk combined scale factors in LDS
  __shared__ float scl[NCH];
  if (t < NCH) scl[t] = __expf(st[t].x - m) * inv;
  __syncthreads();

  // context slice: threads 0..127 own d = x*128 + t
  if (t < 128) {
    const int d = x * 128 + t;
    float a = 0.f;
    for (int cc = 0; cc < NCH; ++cc)
      a += partial[((size_t)b * NCH + cc) * D_ + d] * scl[cc];
    ctx[(size_t)b * D_ + d] = a;
  }

  // weights slice: s = x*1024 + i*256 + t  (elementwise in-place over scores)
#pragma unroll
  for (int i = 0; i < 4; ++i) {
    const size_t s = (size_t)b * S_ + x * 1024 + i * 256 + t;
    weights[s] = __expf(scores[s] - m) * inv;
  }
}

// ---------------------------------------------------------------------------
extern "C" void kernel_launch(void* const* d_in, const int* in_sizes, int n_in,
                              void* d_out, int out_size, void* d_ws, size_t ws_size,
                              hipStream_t stream) {
  const float* q      = (const float*)d_in[0];
  const float* keys   = (const float*)d_in[1];
  const float* values = (const float*)d_in[2];

  float* out     = (float*)d_out;
  float* ctx     = out;               // [B_, D_]
  float* weights = out + B_ * D_;     // [B_, S_] (holds raw scores between kernels)

  f32x4*  partial = (f32x4*)d_ws;                                     // 8 MB
  float2* stats   = (float2*)((char*)d_ws +
                              (size_t)B_ * NCH * D_ * sizeof(float)); // 16 KB

  k_fused<<<dim3(NCH, B_), 256, 0, stream>>>(q, keys, values, weights,
                                             partial, stats);
  k_finalize<<<dim3(8, B_), 256, 0, stream>>>(weights, (const float*)partial,
                                              stats, ctx, weights);
}